// Round 4
// baseline (520.182 us; speedup 1.0000x reference)
//
#include <hip/hip_runtime.h>
#include <math.h>

#define B_ 32
#define S_ 4096
#define CTXD_ 512
#define QD_ 512
#define ATTD_ 256

#define KT 64      // k-chunk (two MFMA K-slices)
#define RT 64      // rows (s) per block

#define MASKED_SCORE (-1e30f)

typedef __attribute__((ext_vector_type(8))) short bf16x8;   // 8 bf16 = 4 VGPR
typedef __attribute__((ext_vector_type(4))) float f32x4;    // MFMA C/D

// fp32 -> bf16 round-to-nearest-even (inputs are finite randoms)
__device__ __forceinline__ unsigned short f2bf(float f) {
    unsigned u = __float_as_uint(f);
    u += 0x7fff + ((u >> 16) & 1);
    return (unsigned short)(u >> 16);
}
__device__ __forceinline__ unsigned pk2(float lo, float hi) {
    return (unsigned)f2bf(lo) | ((unsigned)f2bf(hi) << 16);
}

__device__ __forceinline__ float fast_tanh(float x) {
    float xc = fminf(fmaxf(x, -15.f), 15.f);
    float t = __expf(2.f * xc);
    return (t - 1.f) / (t + 1.f);
}

// ---------------------------------------------------------------------------
// Kernel 0: Wt[n][k] = bf16(W[k][n]) — transpose+convert ctx half of W.
// LDS-tiled: coalesced float4 row reads, uint4 (8xbf16) column writes.
// Grid: 8 blocks x 64 k-rows.
// ---------------------------------------------------------------------------
__global__ __launch_bounds__(256) void wt_kernel(const float* __restrict__ W,
                                                 unsigned short* __restrict__ Wt) {
    __shared__ unsigned short tile[64][266];  // [k][n], pad to break bank cycles
    const int t = threadIdx.x;
    const int kk = blockIdx.x * 64;
    #pragma unroll
    for (int i = 0; i < 16; ++i) {
        const int r = i * 4 + (t >> 6);
        float4 v = ((const float4*)(W + (size_t)(kk + r) * ATTD_))[t & 63];
        unsigned short* tr = &tile[r][(t & 63) * 4];
        tr[0] = f2bf(v.x); tr[1] = f2bf(v.y);
        tr[2] = f2bf(v.z); tr[3] = f2bf(v.w);
    }
    __syncthreads();
    const int l8 = (t & 7) * 8;
    #pragma unroll
    for (int p = 0; p < 8; ++p) {
        const int n = p * 32 + (t >> 3);
        uint4 o;
        o.x = (unsigned)tile[l8 + 0][n] | ((unsigned)tile[l8 + 1][n] << 16);
        o.y = (unsigned)tile[l8 + 2][n] | ((unsigned)tile[l8 + 3][n] << 16);
        o.z = (unsigned)tile[l8 + 4][n] | ((unsigned)tile[l8 + 5][n] << 16);
        o.w = (unsigned)tile[l8 + 6][n] | ((unsigned)tile[l8 + 7][n] << 16);
        *(uint4*)(Wt + (size_t)n * CTXD_ + kk + l8) = o;
    }
}

// ---------------------------------------------------------------------------
// Kernel 1: qh[b][a] = bias[a] + qry[b] @ W_qry  (fp32, tiny)
// ---------------------------------------------------------------------------
__global__ __launch_bounds__(256) void qh_kernel(const float* __restrict__ qry,
                                                 const float* __restrict__ W,
                                                 const float* __restrict__ bias,
                                                 float* __restrict__ qh) {
    __shared__ float q[QD_];
    const int b = blockIdx.x, t = threadIdx.x;
    for (int i = t; i < QD_; i += 256) q[i] = qry[b * QD_ + i];
    __syncthreads();
    float acc = bias[t];
    const float* Wq = W + (size_t)CTXD_ * ATTD_ + t;
    #pragma unroll 8
    for (int k = 0; k < QD_; ++k) acc += q[k] * Wq[(size_t)k * ATTD_];
    qh[b * ATTD_ + t] = acc;
}

// ---------------------------------------------------------------------------
// Kernel 2: MFMA scores. KT=64: 8 chunks, 2 barriers each. Waves tiled 2Mx2N
// (32 rows x 128 cols per wave). Register prefetch of chunk k+1 issued right
// after the store barrier, drained by the next store barrier.
// ---------------------------------------------------------------------------
__global__ __launch_bounds__(256, 3) void scores_kernel(
    const float* __restrict__ ctx, const unsigned short* __restrict__ Wt,
    const float* __restrict__ qh, const float* __restrict__ w2,
    const float* __restrict__ b2, const int* __restrict__ mask,
    float* __restrict__ scores) {
    __shared__ unsigned char lds_a[RT * 144];     // 9216 B
    __shared__ unsigned char lds_b[ATTD_ * 144];  // 36864 B
    const int t = threadIdx.x;
    const int b = blockIdx.y;
    const int s0 = blockIdx.x * RT;
    const int tx = t & 63;  // lane
    const int w = t >> 6;   // wave
    const int wm = w & 1;   // M half: rows wm*32..+32
    const int wn = w >> 1;  // N half: cols wn*128..+128
    const int frow = tx & 15;
    const int fq = tx >> 4;  // 0..3

    f32x4 c00, c01, c02, c03, c04, c05, c06, c07;
    f32x4 c10, c11, c12, c13, c14, c15, c16, c17;
    c00 = c01 = c02 = c03 = c04 = c05 = c06 = c07 = (f32x4)0.f;
    c10 = c11 = c12 = c13 = c14 = c15 = c16 = c17 = (f32x4)0.f;

    const float* ctxb = ctx + ((size_t)b * S_ + s0) * CTXD_;
    const int arow = t >> 2;  // staging row 0..63
    const int akq = t & 3;    // 16-float quarter of the 64-k chunk
    const int bn = t;         // B staging row 0..255

    const unsigned char* aBase = lds_a + (wm * 32 + frow) * 144 + fq * 16;
    const unsigned char* bBase = lds_b + (wn * 128 + frow) * 144 + fq * 16;

    // prefetch chunk 0
    const float* sA = ctxb + (size_t)arow * CTXD_ + akq * 16;
    float4 fa0 = ((const float4*)sA)[0];
    float4 fa1 = ((const float4*)sA)[1];
    float4 fa2 = ((const float4*)sA)[2];
    float4 fa3 = ((const float4*)sA)[3];
    const uint4* sB = (const uint4*)(Wt + (size_t)bn * CTXD_);
    uint4 pb0 = sB[0], pb1 = sB[1], pb2 = sB[2], pb3 = sB[3];
    uint4 pb4 = sB[4], pb5 = sB[5], pb6 = sB[6], pb7 = sB[7];

#define MM1(ni, ks, C0, C1)                                                  \
    {                                                                        \
        bf16x8 bf = *(const bf16x8*)(bBase + (ni) * (16 * 144) + (ks) * 64); \
        C0 = __builtin_amdgcn_mfma_f32_16x16x32_bf16(a0, bf, C0, 0, 0, 0);   \
        C1 = __builtin_amdgcn_mfma_f32_16x16x32_bf16(a1, bf, C1, 0, 0, 0);   \
    }
#define MMK(ks)                                                              \
    {                                                                        \
        bf16x8 a0 = *(const bf16x8*)(aBase + (ks) * 64);                     \
        bf16x8 a1 = *(const bf16x8*)(aBase + 16 * 144 + (ks) * 64);          \
        MM1(0, ks, c00, c10) MM1(1, ks, c01, c11) MM1(2, ks, c02, c12)       \
        MM1(3, ks, c03, c13) MM1(4, ks, c04, c14) MM1(5, ks, c05, c15)       \
        MM1(6, ks, c06, c16) MM1(7, ks, c07, c17)                            \
    }

    #pragma unroll 1
    for (int k0 = 0; k0 < CTXD_; k0 += KT) {
        __syncthreads();  // prior frag reads done; also drains prefetch vmcnt
        {
            uint4 p;
            p.x = pk2(fa0.x, fa0.y); p.y = pk2(fa0.z, fa0.w);
            p.z = pk2(fa1.x, fa1.y); p.w = pk2(fa1.z, fa1.w);
            *(uint4*)(lds_a + arow * 144 + akq * 32) = p;
            p.x = pk2(fa2.x, fa2.y); p.y = pk2(fa2.z, fa2.w);
            p.z = pk2(fa3.x, fa3.y); p.w = pk2(fa3.z, fa3.w);
            *(uint4*)(lds_a + arow * 144 + akq * 32 + 16) = p;
            uint4* bw = (uint4*)(lds_b + bn * 144);
            bw[0] = pb0; bw[1] = pb1; bw[2] = pb2; bw[3] = pb3;
            bw[4] = pb4; bw[5] = pb5; bw[6] = pb6; bw[7] = pb7;
        }
        __syncthreads();
        // issue next chunk's global loads NOW — overlap with MFMA below
        if (k0 + KT < CTXD_) {
            const float* sA2 = ctxb + (size_t)arow * CTXD_ + (k0 + KT) + akq * 16;
            fa0 = ((const float4*)sA2)[0];
            fa1 = ((const float4*)sA2)[1];
            fa2 = ((const float4*)sA2)[2];
            fa3 = ((const float4*)sA2)[3];
            const uint4* sB2 = (const uint4*)(Wt + (size_t)bn * CTXD_ + (k0 + KT));
            pb0 = sB2[0]; pb1 = sB2[1]; pb2 = sB2[2]; pb3 = sB2[3];
            pb4 = sB2[4]; pb5 = sB2[5]; pb6 = sB2[6]; pb7 = sB2[7];
        }
        MMK(0)
        MMK(1)
    }
#undef MMK
#undef MM1

    // Epilogue: lane holds D[row = wm*32 + mi*16 + fq*4 + r][col = wn*128 + ni*16 + frow]
    const float* qhb = qh + b * ATTD_ + wn * 128;
    const float* w2b = w2 + wn * 128;
    float p00 = 0.f, p01 = 0.f, p02 = 0.f, p03 = 0.f;
    float p10 = 0.f, p11 = 0.f, p12 = 0.f, p13 = 0.f;
#define EPI(ni, C0, C1)                                                      \
    {                                                                        \
        float qv = qhb[(ni) * 16 + frow];                                    \
        float wv = w2b[(ni) * 16 + frow];                                    \
        p00 += fast_tanh(C0[0] + qv) * wv;                                   \
        p01 += fast_tanh(C0[1] + qv) * wv;                                   \
        p02 += fast_tanh(C0[2] + qv) * wv;                                   \
        p03 += fast_tanh(C0[3] + qv) * wv;                                   \
        p10 += fast_tanh(C1[0] + qv) * wv;                                   \
        p11 += fast_tanh(C1[1] + qv) * wv;                                   \
        p12 += fast_tanh(C1[2] + qv) * wv;                                   \
        p13 += fast_tanh(C1[3] + qv) * wv;                                   \
    }
    EPI(0, c00, c10) EPI(1, c01, c11) EPI(2, c02, c12) EPI(3, c03, c13)
    EPI(4, c04, c14) EPI(5, c05, c15) EPI(6, c06, c16) EPI(7, c07, c17)
#undef EPI
    // reduce across the 16 frow lanes
    #pragma unroll
    for (int off = 1; off <= 8; off <<= 1) {
        p00 += __shfl_xor(p00, off, 64);
        p01 += __shfl_xor(p01, off, 64);
        p02 += __shfl_xor(p02, off, 64);
        p03 += __shfl_xor(p03, off, 64);
        p10 += __shfl_xor(p10, off, 64);
        p11 += __shfl_xor(p11, off, 64);
        p12 += __shfl_xor(p12, off, 64);
        p13 += __shfl_xor(p13, off, 64);
    }
    // combine the two N-half waves via LDS (reuse lds_a)
    float* sred = (float*)lds_a;  // 128 floats: [wn][row]
    __syncthreads();              // all MFMA-phase LDS reads done
    if (frow == 0) {
        const int base = wn * 64 + wm * 32 + fq * 4;
        sred[base + 0] = p00; sred[base + 1] = p01;
        sred[base + 2] = p02; sred[base + 3] = p03;
        sred[base + 16 + 0] = p10; sred[base + 16 + 1] = p11;
        sred[base + 16 + 2] = p12; sred[base + 16 + 3] = p13;
    }
    __syncthreads();
    if (t < 64) {
        const int s = s0 + t;
        float sc = sred[t] + sred[64 + t] + b2[0];
        if (mask[b * S_ + s] == 0) sc = MASKED_SCORE;
        scores[b * S_ + s] = sc;
    }
}

// ---------------------------------------------------------------------------
// Kernel 3: per-batch softmax stats (m, 1/sum) — shuffle reduce, 2 barriers.
// ---------------------------------------------------------------------------
__global__ __launch_bounds__(256) void softstat_kernel(
    const float* __restrict__ scores, float* __restrict__ stats) {
    const int b = blockIdx.x, t = threadIdx.x;
    __shared__ float red[8];
    float v[16];
    float m = -INFINITY;
    #pragma unroll
    for (int i = 0; i < 16; ++i) {
        v[i] = scores[b * S_ + t + i * 256];
        m = fmaxf(m, v[i]);
    }
    #pragma unroll
    for (int off = 1; off <= 32; off <<= 1) m = fmaxf(m, __shfl_xor(m, off, 64));
    if ((t & 63) == 0) red[t >> 6] = m;
    __syncthreads();
    m = fmaxf(fmaxf(red[0], red[1]), fmaxf(red[2], red[3]));
    float sum = 0.f;
    #pragma unroll
    for (int i = 0; i < 16; ++i) sum += expf(v[i] - m);
    #pragma unroll
    for (int off = 1; off <= 32; off <<= 1) sum += __shfl_xor(sum, off, 64);
    if ((t & 63) == 0) red[4 + (t >> 6)] = sum;
    __syncthreads();
    if (t == 0) {
        sum = red[4] + red[5] + red[6] + red[7];
        stats[2 * b] = m;
        stats[2 * b + 1] = 1.0f / sum;
    }
}

// ---------------------------------------------------------------------------
// Kernel 4: partial summaries (split-S); computes alphas inline from scores
// + stats (VALU headroom), writes the alphas output for its chunk, and
// accumulates the weighted ctx partials. 8-deep load ILP as before.
// ---------------------------------------------------------------------------
__global__ __launch_bounds__(256) void summary_part_kernel(
    const float* __restrict__ ctx, const float* __restrict__ scores,
    const float* __restrict__ stats, float* __restrict__ alphas,
    float* __restrict__ part, int nch, int cs) {
    const int b = blockIdx.y, ch = blockIdx.x, t = threadIdx.x;
    const int col = t & 63;  // float4 index 0..63 (cols 4c and 4c+256)
    const int q = t >> 6;    // 0..3: s ≡ q (mod 4)
    const int s0 = ch * cs;
    const float m = stats[2 * b];
    const float invl = stats[2 * b + 1];
    const float* sp = scores + b * S_ + s0;
    // write alphas output for this chunk (coalesced)
    for (int s = t; s < cs; s += 256)
        alphas[b * S_ + s0 + s] = expf(sp[s] - m) * invl;
    float4 alo = make_float4(0.f, 0.f, 0.f, 0.f);
    float4 ahi = make_float4(0.f, 0.f, 0.f, 0.f);
    const float* cp = ctx + ((size_t)b * S_ + s0) * CTXD_;
    #pragma unroll 4
    for (int s = q; s < cs; s += 4) {
        float al = expf(sp[s] - m) * invl;
        const float4* row = (const float4*)(cp + (size_t)s * CTXD_);
        float4 v0 = row[col];
        float4 v1 = row[col + 64];
        alo.x += v0.x * al; alo.y += v0.y * al;
        alo.z += v0.z * al; alo.w += v0.w * al;
        ahi.x += v1.x * al; ahi.y += v1.y * al;
        ahi.z += v1.z * al; ahi.w += v1.w * al;
    }
    __shared__ float4 buf[4][128];
    buf[q][col] = alo;
    buf[q][col + 64] = ahi;
    __syncthreads();
    if (t < 128) {
        float4 a0 = buf[0][t], a1 = buf[1][t], a2 = buf[2][t], a3 = buf[3][t];
        float4 r;
        r.x = a0.x + a1.x + a2.x + a3.x;
        r.y = a0.y + a1.y + a2.y + a3.y;
        r.z = a0.z + a1.z + a2.z + a3.z;
        r.w = a0.w + a1.w + a2.w + a3.w;
        ((float4*)(part + ((size_t)(b * nch + ch)) * CTXD_))[t] = r;
    }
}

// ---------------------------------------------------------------------------
// Kernel 5: reduce partials -> summary
// ---------------------------------------------------------------------------
__global__ __launch_bounds__(256) void summary_reduce_kernel(
    const float* __restrict__ part, float* __restrict__ summary, int nch) {
    const int b = blockIdx.x, t = threadIdx.x;
    for (int c = t; c < CTXD_; c += 256) {
        float s = 0.f;
        for (int ch = 0; ch < nch; ++ch)
            s += part[((size_t)(b * nch + ch)) * CTXD_ + c];
        summary[b * CTXD_ + c] = s;
    }
}

extern "C" void kernel_launch(void* const* d_in, const int* in_sizes, int n_in,
                              void* d_out, int out_size, void* d_ws,
                              size_t ws_size, hipStream_t stream) {
    const float* qry = (const float*)d_in[0];
    const float* ctx = (const float*)d_in[1];
    const int* mask = (const int*)d_in[2];
    const float* W = (const float*)d_in[3];
    const float* bias = (const float*)d_in[4];
    const float* w2 = (const float*)d_in[5];
    const float* b2 = (const float*)d_in[6];

    float* out = (float*)d_out;
    float* alphas = out;                         // B*S
    float* summary = out + B_ * S_;              // B*CTXD
    float* scores = out + B_ * S_ + B_ * CTXD_;  // B*S

    // ws layout: [Wt bf16 256KB][qh 32KB][stats 256B][part ...]
    unsigned short* Wt = (unsigned short*)d_ws;
    float* qh = (float*)((char*)d_ws + (size_t)ATTD_ * CTXD_ * 2);
    float* stats = qh + B_ * ATTD_;
    float* part = stats + 2 * B_;
    const size_t fixed_bytes =
        (size_t)ATTD_ * CTXD_ * 2 + (size_t)B_ * ATTD_ * 4 + 2 * B_ * 4;

    int nch = 64;
    while (nch > 1 && fixed_bytes + (size_t)B_ * nch * CTXD_ * 4 > ws_size)
        nch >>= 1;
    const int cs = S_ / nch;

    wt_kernel<<<8, 256, 0, stream>>>(W, Wt);
    qh_kernel<<<B_, 256, 0, stream>>>(qry, W, bias, qh);
    scores_kernel<<<dim3(S_ / RT, B_), 256, 0, stream>>>(ctx, Wt, qh, w2, b2,
                                                         mask, scores);
    softstat_kernel<<<B_, 256, 0, stream>>>(scores, stats);
    summary_part_kernel<<<dim3(nch, B_), 256, 0, stream>>>(ctx, scores, stats,
                                                           alphas, part, nch, cs);
    summary_reduce_kernel<<<B_, 256, 0, stream>>>(part, summary, nch);
}

// Round 5
// 470.606 us; speedup vs baseline: 1.1053x; 1.1053x over previous
//
#include <hip/hip_runtime.h>
#include <math.h>

#define B_ 32
#define S_ 4096
#define CTXD_ 512
#define QD_ 512
#define ATTD_ 256

#define KT 64      // k-chunk (two MFMA K-slices)
#define RT 64      // rows (s) per block
#define NCH (S_ / RT)  // 64 chunks per batch row

#define MASKED_SCORE (-1e30f)

typedef __attribute__((ext_vector_type(8))) short bf16x8;   // 8 bf16 = 4 VGPR
typedef __attribute__((ext_vector_type(4))) float f32x4;    // MFMA C/D

// fp32 -> bf16 round-to-nearest-even (inputs are finite randoms)
__device__ __forceinline__ unsigned short f2bf(float f) {
    unsigned u = __float_as_uint(f);
    u += 0x7fff + ((u >> 16) & 1);
    return (unsigned short)(u >> 16);
}
__device__ __forceinline__ unsigned pk2(float lo, float hi) {
    return (unsigned)f2bf(lo) | ((unsigned)f2bf(hi) << 16);
}

__device__ __forceinline__ float fast_tanh(float x) {
    float xc = fminf(fmaxf(x, -15.f), 15.f);
    float t = __expf(2.f * xc);
    return (t - 1.f) / (t + 1.f);
}

// ---------------------------------------------------------------------------
// Kernel 0: Wt[n][k] = bf16(W[k][n]) — transpose+convert ctx half of W.
// LDS-tiled: coalesced float4 row reads, uint4 (8xbf16) column writes.
// ---------------------------------------------------------------------------
__global__ __launch_bounds__(256) void wt_kernel(const float* __restrict__ W,
                                                 unsigned short* __restrict__ Wt) {
    __shared__ unsigned short tile[64][266];  // [k][n], pad to break bank cycles
    const int t = threadIdx.x;
    const int kk = blockIdx.x * 64;
    #pragma unroll
    for (int i = 0; i < 16; ++i) {
        const int r = i * 4 + (t >> 6);
        float4 v = ((const float4*)(W + (size_t)(kk + r) * ATTD_))[t & 63];
        unsigned short* tr = &tile[r][(t & 63) * 4];
        tr[0] = f2bf(v.x); tr[1] = f2bf(v.y);
        tr[2] = f2bf(v.z); tr[3] = f2bf(v.w);
    }
    __syncthreads();
    const int l8 = (t & 7) * 8;
    #pragma unroll
    for (int p = 0; p < 8; ++p) {
        const int n = p * 32 + (t >> 3);
        uint4 o;
        o.x = (unsigned)tile[l8 + 0][n] | ((unsigned)tile[l8 + 1][n] << 16);
        o.y = (unsigned)tile[l8 + 2][n] | ((unsigned)tile[l8 + 3][n] << 16);
        o.z = (unsigned)tile[l8 + 4][n] | ((unsigned)tile[l8 + 5][n] << 16);
        o.w = (unsigned)tile[l8 + 6][n] | ((unsigned)tile[l8 + 7][n] << 16);
        *(uint4*)(Wt + (size_t)n * CTXD_ + kk + l8) = o;
    }
}

// ---------------------------------------------------------------------------
// Kernel 1: qh[b][a] = bias[a] + qry[b] @ W_qry  (fp32, tiny)
// ---------------------------------------------------------------------------
__global__ __launch_bounds__(256) void qh_kernel(const float* __restrict__ qry,
                                                 const float* __restrict__ W,
                                                 const float* __restrict__ bias,
                                                 float* __restrict__ qh) {
    __shared__ float q[QD_];
    const int b = blockIdx.x, t = threadIdx.x;
    for (int i = t; i < QD_; i += 256) q[i] = qry[b * QD_ + i];
    __syncthreads();
    float acc = bias[t];
    const float* Wq = W + (size_t)CTXD_ * ATTD_ + t;
    #pragma unroll 8
    for (int k = 0; k < QD_; ++k) acc += q[k] * Wq[(size_t)k * ATTD_];
    qh[b * ATTD_ + t] = acc;
}

// ---------------------------------------------------------------------------
// Kernel 2: MFMA scores + FUSED local-softmax partial summary (flash-style).
// Per block (64 s-rows): scores as before; then local m/Σexp over the 64
// rows, and the weighted partial summary Σ w_s·ctx[s,:] accumulated from
// L2-hot ctx rows. ctx is read from HBM exactly ONCE in the whole pipeline.
// ---------------------------------------------------------------------------
__global__ __launch_bounds__(256, 3) void scores_kernel(
    const float* __restrict__ ctx, const unsigned short* __restrict__ Wt,
    const float* __restrict__ qh, const float* __restrict__ w2,
    const float* __restrict__ b2, const int* __restrict__ mask,
    float* __restrict__ scores, float* __restrict__ mstat,
    float* __restrict__ lstat, float* __restrict__ part) {
    __shared__ unsigned char lds_a[RT * 144];     // 9216 B
    __shared__ unsigned char lds_b[ATTD_ * 144];  // 36864 B
    const int t = threadIdx.x;
    const int b = blockIdx.y;
    const int ch = blockIdx.x;
    const int s0 = ch * RT;
    const int tx = t & 63;  // lane
    const int w = t >> 6;   // wave
    const int wm = w & 1;   // M half: rows wm*32..+32
    const int wn = w >> 1;  // N half: cols wn*128..+128
    const int frow = tx & 15;
    const int fq = tx >> 4;  // 0..3

    f32x4 c00, c01, c02, c03, c04, c05, c06, c07;
    f32x4 c10, c11, c12, c13, c14, c15, c16, c17;
    c00 = c01 = c02 = c03 = c04 = c05 = c06 = c07 = (f32x4)0.f;
    c10 = c11 = c12 = c13 = c14 = c15 = c16 = c17 = (f32x4)0.f;

    const float* ctxb = ctx + ((size_t)b * S_ + s0) * CTXD_;
    const int arow = t >> 2;  // staging row 0..63
    const int akq = t & 3;    // 16-float quarter of the 64-k chunk
    const int bn = t;         // B staging row 0..255

    const unsigned char* aBase = lds_a + (wm * 32 + frow) * 144 + fq * 16;
    const unsigned char* bBase = lds_b + (wn * 128 + frow) * 144 + fq * 16;

    // prefetch chunk 0
    const float* sA = ctxb + (size_t)arow * CTXD_ + akq * 16;
    float4 fa0 = ((const float4*)sA)[0];
    float4 fa1 = ((const float4*)sA)[1];
    float4 fa2 = ((const float4*)sA)[2];
    float4 fa3 = ((const float4*)sA)[3];
    const uint4* sB = (const uint4*)(Wt + (size_t)bn * CTXD_);
    uint4 pb0 = sB[0], pb1 = sB[1], pb2 = sB[2], pb3 = sB[3];
    uint4 pb4 = sB[4], pb5 = sB[5], pb6 = sB[6], pb7 = sB[7];

#define MM1(ni, ks, C0, C1)                                                  \
    {                                                                        \
        bf16x8 bf = *(const bf16x8*)(bBase + (ni) * (16 * 144) + (ks) * 64); \
        C0 = __builtin_amdgcn_mfma_f32_16x16x32_bf16(a0, bf, C0, 0, 0, 0);   \
        C1 = __builtin_amdgcn_mfma_f32_16x16x32_bf16(a1, bf, C1, 0, 0, 0);   \
    }
#define MMK(ks)                                                              \
    {                                                                        \
        bf16x8 a0 = *(const bf16x8*)(aBase + (ks) * 64);                     \
        bf16x8 a1 = *(const bf16x8*)(aBase + 16 * 144 + (ks) * 64);          \
        MM1(0, ks, c00, c10) MM1(1, ks, c01, c11) MM1(2, ks, c02, c12)       \
        MM1(3, ks, c03, c13) MM1(4, ks, c04, c14) MM1(5, ks, c05, c15)       \
        MM1(6, ks, c06, c16) MM1(7, ks, c07, c17)                            \
    }

    #pragma unroll 1
    for (int k0 = 0; k0 < CTXD_; k0 += KT) {
        __syncthreads();  // prior frag reads done; also drains prefetch vmcnt
        {
            uint4 p;
            p.x = pk2(fa0.x, fa0.y); p.y = pk2(fa0.z, fa0.w);
            p.z = pk2(fa1.x, fa1.y); p.w = pk2(fa1.z, fa1.w);
            *(uint4*)(lds_a + arow * 144 + akq * 32) = p;
            p.x = pk2(fa2.x, fa2.y); p.y = pk2(fa2.z, fa2.w);
            p.z = pk2(fa3.x, fa3.y); p.w = pk2(fa3.z, fa3.w);
            *(uint4*)(lds_a + arow * 144 + akq * 32 + 16) = p;
            uint4* bw = (uint4*)(lds_b + bn * 144);
            bw[0] = pb0; bw[1] = pb1; bw[2] = pb2; bw[3] = pb3;
            bw[4] = pb4; bw[5] = pb5; bw[6] = pb6; bw[7] = pb7;
        }
        __syncthreads();
        // issue next chunk's global loads NOW — overlap with MFMA below
        if (k0 + KT < CTXD_) {
            const float* sA2 = ctxb + (size_t)arow * CTXD_ + (k0 + KT) + akq * 16;
            fa0 = ((const float4*)sA2)[0];
            fa1 = ((const float4*)sA2)[1];
            fa2 = ((const float4*)sA2)[2];
            fa3 = ((const float4*)sA2)[3];
            const uint4* sB2 = (const uint4*)(Wt + (size_t)bn * CTXD_ + (k0 + KT));
            pb0 = sB2[0]; pb1 = sB2[1]; pb2 = sB2[2]; pb3 = sB2[3];
            pb4 = sB2[4]; pb5 = sB2[5]; pb6 = sB2[6]; pb7 = sB2[7];
        }
        MMK(0)
        MMK(1)
    }
#undef MMK
#undef MM1

    // Epilogue: lane holds D[row = wm*32 + mi*16 + fq*4 + r][col = wn*128 + ni*16 + frow]
    const float* qhb = qh + b * ATTD_ + wn * 128;
    const float* w2b = w2 + wn * 128;
    float p00 = 0.f, p01 = 0.f, p02 = 0.f, p03 = 0.f;
    float p10 = 0.f, p11 = 0.f, p12 = 0.f, p13 = 0.f;
#define EPI(ni, C0, C1)                                                      \
    {                                                                        \
        float qv = qhb[(ni) * 16 + frow];                                    \
        float wv = w2b[(ni) * 16 + frow];                                    \
        p00 += fast_tanh(C0[0] + qv) * wv;                                   \
        p01 += fast_tanh(C0[1] + qv) * wv;                                   \
        p02 += fast_tanh(C0[2] + qv) * wv;                                   \
        p03 += fast_tanh(C0[3] + qv) * wv;                                   \
        p10 += fast_tanh(C1[0] + qv) * wv;                                   \
        p11 += fast_tanh(C1[1] + qv) * wv;                                   \
        p12 += fast_tanh(C1[2] + qv) * wv;                                   \
        p13 += fast_tanh(C1[3] + qv) * wv;                                   \
    }
    EPI(0, c00, c10) EPI(1, c01, c11) EPI(2, c02, c12) EPI(3, c03, c13)
    EPI(4, c04, c14) EPI(5, c05, c15) EPI(6, c06, c16) EPI(7, c07, c17)
#undef EPI
    // reduce across the 16 frow lanes
    #pragma unroll
    for (int off = 1; off <= 8; off <<= 1) {
        p00 += __shfl_xor(p00, off, 64);
        p01 += __shfl_xor(p01, off, 64);
        p02 += __shfl_xor(p02, off, 64);
        p03 += __shfl_xor(p03, off, 64);
        p10 += __shfl_xor(p10, off, 64);
        p11 += __shfl_xor(p11, off, 64);
        p12 += __shfl_xor(p12, off, 64);
        p13 += __shfl_xor(p13, off, 64);
    }
    // combine the two N-half waves via LDS (reuse lds_a)
    float* sred = (float*)lds_a;  // 128 floats: [wn][row]
    __syncthreads();              // all MFMA-phase LDS reads done
    if (frow == 0) {
        const int base = wn * 64 + wm * 32 + fq * 4;
        sred[base + 0] = p00; sred[base + 1] = p01;
        sred[base + 2] = p02; sred[base + 3] = p03;
        sred[base + 16 + 0] = p10; sred[base + 16 + 1] = p11;
        sred[base + 16 + 2] = p12; sred[base + 16 + 3] = p13;
    }
    __syncthreads();
    // --- local softmax over this block's 64 rows (wave 0 only) ---
    float* wl = (float*)lds_b;  // 64 weights (lds_b done with MFMA phase)
    if (t < 64) {
        const int s = s0 + t;
        float sc = sred[t] + sred[64 + t] + b2[0];
        const bool msk = (mask[b * S_ + s] == 0);
        if (msk) sc = MASKED_SCORE;
        scores[b * S_ + s] = sc;
        // local max over the 64 rows (finite sentinel, no inf arithmetic)
        float mloc = sc;
        #pragma unroll
        for (int off = 1; off < 64; off <<= 1)
            mloc = fmaxf(mloc, __shfl_xor(mloc, off, 64));
        const float ws = msk ? 0.f : __expf(sc - mloc);
        float lloc = ws;
        #pragma unroll
        for (int off = 1; off < 64; off <<= 1)
            lloc += __shfl_xor(lloc, off, 64);
        if (t == 0) {
            mstat[b * NCH + ch] = mloc;
            lstat[b * NCH + ch] = lloc;
        }
        wl[t] = ws;
    }
    __syncthreads();
    // --- partial summary: Σ_s w_s · ctx[s,:]  (ctx rows are L2-hot) ---
    const int col = t & 63;  // float4 col idx (cols col and col+64)
    const int q = t >> 6;    // s ≡ q (mod 4)
    float4 alo = make_float4(0.f, 0.f, 0.f, 0.f);
    float4 ahi = make_float4(0.f, 0.f, 0.f, 0.f);
    #pragma unroll 4
    for (int s = q; s < RT; s += 4) {
        const float al = wl[s];
        const float4* row = (const float4*)(ctxb + (size_t)s * CTXD_);
        float4 v0 = row[col];
        float4 v1 = row[col + 64];
        alo.x += v0.x * al; alo.y += v0.y * al;
        alo.z += v0.z * al; alo.w += v0.w * al;
        ahi.x += v1.x * al; ahi.y += v1.y * al;
        ahi.z += v1.z * al; ahi.w += v1.w * al;
    }
    float4* buf = (float4*)(lds_b + 1024);  // disjoint from wl[0..63]
    buf[q * 128 + col] = alo;
    buf[q * 128 + col + 64] = ahi;
    __syncthreads();
    if (t < 128) {
        float4 a0 = buf[t], a1 = buf[128 + t], a2 = buf[256 + t], a3 = buf[384 + t];
        float4 r;
        r.x = a0.x + a1.x + a2.x + a3.x;
        r.y = a0.y + a1.y + a2.y + a3.y;
        r.z = a0.z + a1.z + a2.z + a3.z;
        r.w = a0.w + a1.w + a2.w + a3.w;
        ((float4*)(part + ((size_t)(b * NCH + ch)) * CTXD_))[t] = r;
    }
}

// ---------------------------------------------------------------------------
// Kernel 3: combine — per batch row: global (m, 1/l) from per-chunk stats,
// flash-rescale + reduce the 64 partial summaries, write summary + alphas.
// ---------------------------------------------------------------------------
__global__ __launch_bounds__(256) void combine_kernel(
    const float* __restrict__ mstat, const float* __restrict__ lstat,
    const float* __restrict__ part, const float* __restrict__ scores,
    float* __restrict__ alphas, float* __restrict__ summary) {
    const int b = blockIdx.x, t = threadIdx.x;
    __shared__ float e[NCH];
    __shared__ float gstat[2];  // m, invl
    if (t < NCH) {
        const float mi = mstat[b * NCH + t];
        const float li = lstat[b * NCH + t];
        float m = mi;
        #pragma unroll
        for (int off = 1; off < 64; off <<= 1)
            m = fmaxf(m, __shfl_xor(m, off, 64));
        const float ei = __expf(mi - m);  // all-masked chunk: underflows to 0
        float l = ei * li;
        #pragma unroll
        for (int off = 1; off < 64; off <<= 1)
            l += __shfl_xor(l, off, 64);
        e[t] = ei;
        if (t == 0) { gstat[0] = m; gstat[1] = 1.0f / l; }
    }
    __syncthreads();
    const float m = gstat[0], il = gstat[1];
    // summary = invl * Σ_ch e_ch · part[ch][:]
    const int c4 = t & 127, h = t >> 7;
    float4 acc = make_float4(0.f, 0.f, 0.f, 0.f);
    for (int chv = h; chv < NCH; chv += 2) {
        const float ei = e[chv];
        float4 v = ((const float4*)(part + ((size_t)(b * NCH + chv)) * CTXD_))[c4];
        acc.x += ei * v.x; acc.y += ei * v.y;
        acc.z += ei * v.z; acc.w += ei * v.w;
    }
    __shared__ float4 buf[128];
    if (h == 1) buf[c4] = acc;
    __syncthreads();
    if (h == 0) {
        float4 o = buf[c4];
        acc.x = (acc.x + o.x) * il; acc.y = (acc.y + o.y) * il;
        acc.z = (acc.z + o.z) * il; acc.w = (acc.w + o.w) * il;
        ((float4*)(summary + (size_t)b * CTXD_))[c4] = acc;
    }
    // alphas from stored scores (masked rows: -1e30 → exp underflows to 0)
    for (int s = t; s < S_; s += 256)
        alphas[b * S_ + s] = __expf(scores[b * S_ + s] - m) * il;
}

extern "C" void kernel_launch(void* const* d_in, const int* in_sizes, int n_in,
                              void* d_out, int out_size, void* d_ws,
                              size_t ws_size, hipStream_t stream) {
    const float* qry = (const float*)d_in[0];
    const float* ctx = (const float*)d_in[1];
    const int* mask = (const int*)d_in[2];
    const float* W = (const float*)d_in[3];
    const float* bias = (const float*)d_in[4];
    const float* w2 = (const float*)d_in[5];
    const float* b2 = (const float*)d_in[6];

    float* out = (float*)d_out;
    float* alphas = out;                         // B*S
    float* summary = out + B_ * S_;              // B*CTXD
    float* scores = out + B_ * S_ + B_ * CTXD_;  // B*S

    // ws layout: [Wt bf16 256KB][qh 32KB][mstat 8KB][lstat 8KB][part 4MB]
    unsigned short* Wt = (unsigned short*)d_ws;
    float* qh = (float*)((char*)d_ws + (size_t)ATTD_ * CTXD_ * 2);
    float* mstat = qh + B_ * ATTD_;
    float* lstat = mstat + B_ * NCH;
    float* part = lstat + B_ * NCH;

    wt_kernel<<<8, 256, 0, stream>>>(W, Wt);
    qh_kernel<<<B_, 256, 0, stream>>>(qry, W, bias, qh);
    scores_kernel<<<dim3(NCH, B_), 256, 0, stream>>>(ctx, Wt, qh, w2, b2, mask,
                                                     scores, mstat, lstat, part);
    combine_kernel<<<B_, 256, 0, stream>>>(mstat, lstat, part, scores, alphas,
                                           summary);
}

// Round 7
// 449.084 us; speedup vs baseline: 1.1583x; 1.0479x over previous
//
#include <hip/hip_runtime.h>
#include <math.h>

#define B_ 32
#define S_ 4096
#define CTXD_ 512
#define QD_ 512
#define ATTD_ 256

#define KT 64      // k-chunk (two MFMA K-slices)
#define RT 64      // rows (s) per block
#define NCH (S_ / RT)  // 64 chunks per batch row

#define MASKED_SCORE (-1e30f)

typedef __attribute__((ext_vector_type(8))) short bf16x8;   // 8 bf16 = 4 VGPR
typedef __attribute__((ext_vector_type(4))) float f32x4;    // MFMA C/D

// fp32 -> bf16 round-to-nearest-even (inputs are finite randoms)
__device__ __forceinline__ unsigned short f2bf(float f) {
    unsigned u = __float_as_uint(f);
    u += 0x7fff + ((u >> 16) & 1);
    return (unsigned short)(u >> 16);
}
__device__ __forceinline__ unsigned pk2(float lo, float hi) {
    return (unsigned)f2bf(lo) | ((unsigned)f2bf(hi) << 16);
}

__device__ __forceinline__ float fast_tanh(float x) {
    float xc = fminf(fmaxf(x, -15.f), 15.f);
    float t = __expf(2.f * xc);
    return (t - 1.f) / (t + 1.f);
}

// ---------------------------------------------------------------------------
// Kernel 0 (fused prep): blocks 0..31 transpose+convert W_ctx -> Wt bf16
// (64x64 tiles, 32 blocks); blocks 32..63 compute qh[b] = bias + qry[b]@W_qry.
// One launch, 64 blocks, replaces two narrow serialized kernels.
// ---------------------------------------------------------------------------
__global__ __launch_bounds__(256) void prep_kernel(
    const float* __restrict__ W, const float* __restrict__ qry,
    const float* __restrict__ bias, unsigned short* __restrict__ Wt,
    float* __restrict__ qh) {
    __shared__ unsigned char lds[64 * 66 * 2];  // wt tile (8448 B) / qh q (2048 B)
    const int bid = blockIdx.x;
    const int t = threadIdx.x;
    if (bid < 32) {
        // --- Wt tile: k-rows kk..kk+64, n-cols nn..nn+64 ---
        unsigned short(*tile)[66] = (unsigned short(*)[66])lds;
        const int kk = (bid >> 2) * 64;
        const int nn = (bid & 3) * 64;
        #pragma unroll
        for (int i = 0; i < 4; ++i) {
            const int r = i * 16 + (t >> 4);
            float4 v = ((const float4*)(W + (size_t)(kk + r) * ATTD_ + nn))[t & 15];
            unsigned short* tr = &tile[r][(t & 15) * 4];
            tr[0] = f2bf(v.x); tr[1] = f2bf(v.y);
            tr[2] = f2bf(v.z); tr[3] = f2bf(v.w);
        }
        __syncthreads();
        const int l8 = (t & 7) * 8;
        #pragma unroll
        for (int p = 0; p < 2; ++p) {
            const int n = p * 32 + (t >> 3);
            uint4 o;
            o.x = (unsigned)tile[l8 + 0][n] | ((unsigned)tile[l8 + 1][n] << 16);
            o.y = (unsigned)tile[l8 + 2][n] | ((unsigned)tile[l8 + 3][n] << 16);
            o.z = (unsigned)tile[l8 + 4][n] | ((unsigned)tile[l8 + 5][n] << 16);
            o.w = (unsigned)tile[l8 + 6][n] | ((unsigned)tile[l8 + 7][n] << 16);
            *(uint4*)(Wt + (size_t)(nn + n) * CTXD_ + kk + l8) = o;
        }
    } else {
        // --- qh row b = bid-32 ---
        float* q = (float*)lds;
        const int b = bid - 32;
        for (int i = t; i < QD_; i += 256) q[i] = qry[b * QD_ + i];
        __syncthreads();
        float acc = bias[t];
        const float* Wq = W + (size_t)CTXD_ * ATTD_ + t;
        #pragma unroll 8
        for (int k = 0; k < QD_; ++k) acc += q[k] * Wq[(size_t)k * ATTD_];
        qh[b * ATTD_ + t] = acc;
    }
}

// ---------------------------------------------------------------------------
// Kernel 1: MFMA scores + FUSED local-softmax partial summary (flash-style).
// Per block (64 s-rows): scores; local m/Σexp over the 64 rows; weighted
// partial summary Σ w_s·ctx[s,:] from L2-hot ctx rows. ctx is read from HBM
// exactly ONCE in the whole pipeline.
// ---------------------------------------------------------------------------
__global__ __launch_bounds__(256, 3) void scores_kernel(
    const float* __restrict__ ctx, const unsigned short* __restrict__ Wt,
    const float* __restrict__ qh, const float* __restrict__ w2,
    const float* __restrict__ b2, const int* __restrict__ mask,
    float* __restrict__ scores, float* __restrict__ mstat,
    float* __restrict__ lstat, float* __restrict__ part) {
    __shared__ unsigned char lds_a[RT * 144];     // 9216 B
    __shared__ unsigned char lds_b[ATTD_ * 144];  // 36864 B
    const int t = threadIdx.x;
    const int b = blockIdx.y;
    const int ch = blockIdx.x;
    const int s0 = ch * RT;
    const int tx = t & 63;  // lane
    const int w = t >> 6;   // wave
    const int wm = w & 1;   // M half: rows wm*32..+32
    const int wn = w >> 1;  // N half: cols wn*128..+128
    const int frow = tx & 15;
    const int fq = tx >> 4;  // 0..3

    f32x4 c00, c01, c02, c03, c04, c05, c06, c07;
    f32x4 c10, c11, c12, c13, c14, c15, c16, c17;
    c00 = c01 = c02 = c03 = c04 = c05 = c06 = c07 = (f32x4)0.f;
    c10 = c11 = c12 = c13 = c14 = c15 = c16 = c17 = (f32x4)0.f;

    const float* ctxb = ctx + ((size_t)b * S_ + s0) * CTXD_;
    const int arow = t >> 2;  // staging row 0..63
    const int akq = t & 3;    // 16-float quarter of the 64-k chunk
    const int bn = t;         // B staging row 0..255

    const unsigned char* aBase = lds_a + (wm * 32 + frow) * 144 + fq * 16;
    const unsigned char* bBase = lds_b + (wn * 128 + frow) * 144 + fq * 16;

    // prefetch chunk 0
    const float* sA = ctxb + (size_t)arow * CTXD_ + akq * 16;
    float4 fa0 = ((const float4*)sA)[0];
    float4 fa1 = ((const float4*)sA)[1];
    float4 fa2 = ((const float4*)sA)[2];
    float4 fa3 = ((const float4*)sA)[3];
    const uint4* sB = (const uint4*)(Wt + (size_t)bn * CTXD_);
    uint4 pb0 = sB[0], pb1 = sB[1], pb2 = sB[2], pb3 = sB[3];
    uint4 pb4 = sB[4], pb5 = sB[5], pb6 = sB[6], pb7 = sB[7];

#define MM1(ni, ks, C0, C1)                                                  \
    {                                                                        \
        bf16x8 bf = *(const bf16x8*)(bBase + (ni) * (16 * 144) + (ks) * 64); \
        C0 = __builtin_amdgcn_mfma_f32_16x16x32_bf16(a0, bf, C0, 0, 0, 0);   \
        C1 = __builtin_amdgcn_mfma_f32_16x16x32_bf16(a1, bf, C1, 0, 0, 0);   \
    }
#define MMK(ks)                                                              \
    {                                                                        \
        bf16x8 a0 = *(const bf16x8*)(aBase + (ks) * 64);                     \
        bf16x8 a1 = *(const bf16x8*)(aBase + 16 * 144 + (ks) * 64);          \
        MM1(0, ks, c00, c10) MM1(1, ks, c01, c11) MM1(2, ks, c02, c12)       \
        MM1(3, ks, c03, c13) MM1(4, ks, c04, c14) MM1(5, ks, c05, c15)       \
        MM1(6, ks, c06, c16) MM1(7, ks, c07, c17)                            \
    }

    #pragma unroll 1
    for (int k0 = 0; k0 < CTXD_; k0 += KT) {
        __syncthreads();  // prior frag reads done; also drains prefetch vmcnt
        {
            uint4 p;
            p.x = pk2(fa0.x, fa0.y); p.y = pk2(fa0.z, fa0.w);
            p.z = pk2(fa1.x, fa1.y); p.w = pk2(fa1.z, fa1.w);
            *(uint4*)(lds_a + arow * 144 + akq * 32) = p;
            p.x = pk2(fa2.x, fa2.y); p.y = pk2(fa2.z, fa2.w);
            p.z = pk2(fa3.x, fa3.y); p.w = pk2(fa3.z, fa3.w);
            *(uint4*)(lds_a + arow * 144 + akq * 32 + 16) = p;
            uint4* bw = (uint4*)(lds_b + bn * 144);
            bw[0] = pb0; bw[1] = pb1; bw[2] = pb2; bw[3] = pb3;
            bw[4] = pb4; bw[5] = pb5; bw[6] = pb6; bw[7] = pb7;
        }
        __syncthreads();
        // issue next chunk's global loads NOW — overlap with MFMA below
        if (k0 + KT < CTXD_) {
            const float* sA2 = ctxb + (size_t)arow * CTXD_ + (k0 + KT) + akq * 16;
            fa0 = ((const float4*)sA2)[0];
            fa1 = ((const float4*)sA2)[1];
            fa2 = ((const float4*)sA2)[2];
            fa3 = ((const float4*)sA2)[3];
            const uint4* sB2 = (const uint4*)(Wt + (size_t)bn * CTXD_ + (k0 + KT));
            pb0 = sB2[0]; pb1 = sB2[1]; pb2 = sB2[2]; pb3 = sB2[3];
            pb4 = sB2[4]; pb5 = sB2[5]; pb6 = sB2[6]; pb7 = sB2[7];
        }
        MMK(0)
        MMK(1)
    }
#undef MMK
#undef MM1

    // Epilogue: lane holds D[row = wm*32 + mi*16 + fq*4 + r][col = wn*128 + ni*16 + frow]
    const float* qhb = qh + b * ATTD_ + wn * 128;
    const float* w2b = w2 + wn * 128;
    float p00 = 0.f, p01 = 0.f, p02 = 0.f, p03 = 0.f;
    float p10 = 0.f, p11 = 0.f, p12 = 0.f, p13 = 0.f;
#define EPI(ni, C0, C1)                                                      \
    {                                                                        \
        float qv = qhb[(ni) * 16 + frow];                                    \
        float wv = w2b[(ni) * 16 + frow];                                    \
        p00 += fast_tanh(C0[0] + qv) * wv;                                   \
        p01 += fast_tanh(C0[1] + qv) * wv;                                   \
        p02 += fast_tanh(C0[2] + qv) * wv;                                   \
        p03 += fast_tanh(C0[3] + qv) * wv;                                   \
        p10 += fast_tanh(C1[0] + qv) * wv;                                   \
        p11 += fast_tanh(C1[1] + qv) * wv;                                   \
        p12 += fast_tanh(C1[2] + qv) * wv;                                   \
        p13 += fast_tanh(C1[3] + qv) * wv;                                   \
    }
    EPI(0, c00, c10) EPI(1, c01, c11) EPI(2, c02, c12) EPI(3, c03, c13)
    EPI(4, c04, c14) EPI(5, c05, c15) EPI(6, c06, c16) EPI(7, c07, c17)
#undef EPI
    // reduce across the 16 frow lanes
    #pragma unroll
    for (int off = 1; off <= 8; off <<= 1) {
        p00 += __shfl_xor(p00, off, 64);
        p01 += __shfl_xor(p01, off, 64);
        p02 += __shfl_xor(p02, off, 64);
        p03 += __shfl_xor(p03, off, 64);
        p10 += __shfl_xor(p10, off, 64);
        p11 += __shfl_xor(p11, off, 64);
        p12 += __shfl_xor(p12, off, 64);
        p13 += __shfl_xor(p13, off, 64);
    }
    // combine the two N-half waves via LDS (reuse lds_a)
    float* sred = (float*)lds_a;  // 128 floats: [wn][row]
    __syncthreads();              // all MFMA-phase LDS reads done
    if (frow == 0) {
        const int base = wn * 64 + wm * 32 + fq * 4;
        sred[base + 0] = p00; sred[base + 1] = p01;
        sred[base + 2] = p02; sred[base + 3] = p03;
        sred[base + 16 + 0] = p10; sred[base + 16 + 1] = p11;
        sred[base + 16 + 2] = p12; sred[base + 16 + 3] = p13;
    }
    __syncthreads();
    // --- local softmax over this block's 64 rows (wave 0 only) ---
    float* wl = (float*)lds_b;  // 64 weights (lds_b done with MFMA phase)
    if (t < 64) {
        const int s = s0 + t;
        float sc = sred[t] + sred[64 + t] + b2[0];
        const bool msk = (mask[b * S_ + s] == 0);
        if (msk) sc = MASKED_SCORE;
        scores[b * S_ + s] = sc;
        // local max over the 64 rows (finite sentinel, no inf arithmetic)
        float mloc = sc;
        #pragma unroll
        for (int off = 1; off < 64; off <<= 1)
            mloc = fmaxf(mloc, __shfl_xor(mloc, off, 64));
        const float ws = msk ? 0.f : __expf(sc - mloc);
        float lloc = ws;
        #pragma unroll
        for (int off = 1; off < 64; off <<= 1)
            lloc += __shfl_xor(lloc, off, 64);
        if (t == 0) {
            mstat[b * NCH + ch] = mloc;
            lstat[b * NCH + ch] = lloc;
        }
        wl[t] = ws;
    }
    __syncthreads();
    // --- partial summary: Σ_s w_s · ctx[s,:]  (ctx rows are L2-hot) ---
    const int col = t & 63;  // float4 col idx (cols col and col+64)
    const int q = t >> 6;    // s ≡ q (mod 4)
    float4 alo = make_float4(0.f, 0.f, 0.f, 0.f);
    float4 ahi = make_float4(0.f, 0.f, 0.f, 0.f);
    #pragma unroll 4
    for (int s = q; s < RT; s += 4) {
        const float al = wl[s];
        const float4* row = (const float4*)(ctxb + (size_t)s * CTXD_);
        float4 v0 = row[col];
        float4 v1 = row[col + 64];
        alo.x += v0.x * al; alo.y += v0.y * al;
        alo.z += v0.z * al; alo.w += v0.w * al;
        ahi.x += v1.x * al; ahi.y += v1.y * al;
        ahi.z += v1.z * al; ahi.w += v1.w * al;
    }
    float4* buf = (float4*)(lds_b + 1024);  // disjoint from wl[0..63]
    buf[q * 128 + col] = alo;
    buf[q * 128 + col + 64] = ahi;
    __syncthreads();
    if (t < 128) {
        float4 a0 = buf[t], a1 = buf[128 + t], a2 = buf[256 + t], a3 = buf[384 + t];
        float4 r;
        r.x = a0.x + a1.x + a2.x + a3.x;
        r.y = a0.y + a1.y + a2.y + a3.y;
        r.z = a0.z + a1.z + a2.z + a3.z;
        r.w = a0.w + a1.w + a2.w + a3.w;
        ((float4*)(part + ((size_t)(b * NCH + ch)) * CTXD_))[t] = r;
    }
}

// ---------------------------------------------------------------------------
// Kernel 2: combine — grid (4, B). Each block redoes the cheap per-chunk
// stats reduce, then handles a 128-col slice of summary and a 1024-row slice
// of alphas. 128 blocks instead of 32 → 4x CU coverage for the tail.
// ---------------------------------------------------------------------------
__global__ __launch_bounds__(256) void combine_kernel(
    const float* __restrict__ mstat, const float* __restrict__ lstat,
    const float* __restrict__ part, const float* __restrict__ scores,
    float* __restrict__ alphas, float* __restrict__ summary) {
    const int b = blockIdx.y, seg = blockIdx.x, t = threadIdx.x;
    __shared__ float e[NCH];
    __shared__ float gstat[2];  // m, invl
    if (t < NCH) {
        const float mi = mstat[b * NCH + t];
        const float li = lstat[b * NCH + t];
        float m = mi;
        #pragma unroll
        for (int off = 1; off < 64; off <<= 1)
            m = fmaxf(m, __shfl_xor(m, off, 64));
        const float ei = __expf(mi - m);  // all-masked chunk: underflows to 0
        float l = ei * li;
        #pragma unroll
        for (int off = 1; off < 64; off <<= 1)
            l += __shfl_xor(l, off, 64);
        e[t] = ei;
        if (t == 0) { gstat[0] = m; gstat[1] = 1.0f / l; }
    }
    __syncthreads();
    const float m = gstat[0], il = gstat[1];
    // summary slice: cols [seg*128, seg*128+128) = 32 float4
    const int c4 = t & 31;   // float4 within slice
    const int grp = t >> 5;  // 0..7: chunk phase
    float4 acc = make_float4(0.f, 0.f, 0.f, 0.f);
    for (int chv = grp; chv < NCH; chv += 8) {
        const float ei = e[chv];
        float4 v =
            ((const float4*)(part + ((size_t)(b * NCH + chv)) * CTXD_ + seg * 128))[c4];
        acc.x += ei * v.x; acc.y += ei * v.y;
        acc.z += ei * v.z; acc.w += ei * v.w;
    }
    __shared__ float4 buf[8][32];
    buf[grp][c4] = acc;
    __syncthreads();
    if (t < 32) {
        float4 r = make_float4(0.f, 0.f, 0.f, 0.f);
        #pragma unroll
        for (int g = 0; g < 8; ++g) {
            float4 v = buf[g][t];
            r.x += v.x; r.y += v.y; r.z += v.z; r.w += v.w;
        }
        r.x *= il; r.y *= il; r.z *= il; r.w *= il;
        ((float4*)(summary + (size_t)b * CTXD_ + seg * 128))[t] = r;
    }
    // alphas slice: s in [seg*1024, +1024)
    const int sbase = seg * 1024;
    #pragma unroll
    for (int i = 0; i < 4; ++i) {
        const int s = sbase + i * 256 + t;
        alphas[b * S_ + s] = __expf(scores[b * S_ + s] - m) * il;
    }
}

extern "C" void kernel_launch(void* const* d_in, const int* in_sizes, int n_in,
                              void* d_out, int out_size, void* d_ws,
                              size_t ws_size, hipStream_t stream) {
    const float* qry = (const float*)d_in[0];
    const float* ctx = (const float*)d_in[1];
    const int* mask = (const int*)d_in[2];
    const float* W = (const float*)d_in[3];
    const float* bias = (const float*)d_in[4];
    const float* w2 = (const float*)d_in[5];
    const float* b2 = (const float*)d_in[6];

    float* out = (float*)d_out;
    float* alphas = out;                         // B*S
    float* summary = out + B_ * S_;              // B*CTXD
    float* scores = out + B_ * S_ + B_ * CTXD_;  // B*S

    // ws layout: [Wt bf16 256KB][qh 32KB][mstat 8KB][lstat 8KB][part 4MB]
    unsigned short* Wt = (unsigned short*)d_ws;
    float* qh = (float*)((char*)d_ws + (size_t)ATTD_ * CTXD_ * 2);
    float* mstat = qh + B_ * ATTD_;
    float* lstat = mstat + B_ * NCH;
    float* part = lstat + B_ * NCH;

    prep_kernel<<<64, 256, 0, stream>>>(W, qry, bias, Wt, qh);
    scores_kernel<<<dim3(NCH, B_), 256, 0, stream>>>(ctx, Wt, qh, w2, b2, mask,
                                                     scores, mstat, lstat, part);
    combine_kernel<<<dim3(4, B_), 256, 0, stream>>>(mstat, lstat, part, scores,
                                                    alphas, summary);
}

// Round 9
// 444.771 us; speedup vs baseline: 1.1696x; 1.0097x over previous
//
#include <hip/hip_runtime.h>
#include <math.h>

#define B_ 32
#define S_ 4096
#define CTXD_ 512
#define QD_ 512
#define ATTD_ 256

#define KT 64        // k-chunk (two MFMA K-slices)
#define RT 128       // rows (s) per block
#define NCH (S_ / RT)  // 32 chunks per batch row

#define MASKED_SCORE (-1e30f)

typedef __attribute__((ext_vector_type(8))) short bf16x8;   // 8 bf16 = 4 VGPR
typedef __attribute__((ext_vector_type(4))) float f32x4;    // MFMA C/D

// fp32 -> bf16 round-to-nearest-even (inputs are finite randoms)
__device__ __forceinline__ unsigned short f2bf(float f) {
    unsigned u = __float_as_uint(f);
    u += 0x7fff + ((u >> 16) & 1);
    return (unsigned short)(u >> 16);
}
__device__ __forceinline__ unsigned pk2(float lo, float hi) {
    return (unsigned)f2bf(lo) | ((unsigned)f2bf(hi) << 16);
}

__device__ __forceinline__ float fast_tanh(float x) {
    float xc = fminf(fmaxf(x, -15.f), 15.f);
    float t = __expf(2.f * xc);
    return (t - 1.f) / (t + 1.f);
}

// ---------------------------------------------------------------------------
// Kernel 0 (fused prep): blocks 0..31 transpose+convert W_ctx -> Wt bf16
// (64x64 tiles); blocks 32..63 compute qh[b] = bias + qry[b]@W_qry.
// ---------------------------------------------------------------------------
__global__ __launch_bounds__(256) void prep_kernel(
    const float* __restrict__ W, const float* __restrict__ qry,
    const float* __restrict__ bias, unsigned short* __restrict__ Wt,
    float* __restrict__ qh) {
    __shared__ unsigned char lds[64 * 66 * 2];  // wt tile (8448 B) / qh q (2048 B)
    const int bid = blockIdx.x;
    const int t = threadIdx.x;
    if (bid < 32) {
        // --- Wt tile: k-rows kk..kk+64, n-cols nn..nn+64 ---
        unsigned short(*tile)[66] = (unsigned short(*)[66])lds;
        const int kk = (bid >> 2) * 64;
        const int nn = (bid & 3) * 64;
        #pragma unroll
        for (int i = 0; i < 4; ++i) {
            const int r = i * 16 + (t >> 4);
            float4 v = ((const float4*)(W + (size_t)(kk + r) * ATTD_ + nn))[t & 15];
            unsigned short* tr = &tile[r][(t & 15) * 4];
            tr[0] = f2bf(v.x); tr[1] = f2bf(v.y);
            tr[2] = f2bf(v.z); tr[3] = f2bf(v.w);
        }
        __syncthreads();
        const int l8 = (t & 7) * 8;
        #pragma unroll
        for (int p = 0; p < 2; ++p) {
            const int n = p * 32 + (t >> 3);
            uint4 o;
            o.x = (unsigned)tile[l8 + 0][n] | ((unsigned)tile[l8 + 1][n] << 16);
            o.y = (unsigned)tile[l8 + 2][n] | ((unsigned)tile[l8 + 3][n] << 16);
            o.z = (unsigned)tile[l8 + 4][n] | ((unsigned)tile[l8 + 5][n] << 16);
            o.w = (unsigned)tile[l8 + 6][n] | ((unsigned)tile[l8 + 7][n] << 16);
            *(uint4*)(Wt + (size_t)(nn + n) * CTXD_ + kk + l8) = o;
        }
    } else {
        // --- qh row b = bid-32 ---
        float* q = (float*)lds;
        const int b = bid - 32;
        for (int i = t; i < QD_; i += 256) q[i] = qry[b * QD_ + i];
        __syncthreads();
        float acc = bias[t];
        const float* Wq = W + (size_t)CTXD_ * ATTD_ + t;
        #pragma unroll 8
        for (int k = 0; k < QD_; ++k) acc += q[k] * Wq[(size_t)k * ATTD_];
        qh[b * ATTD_ + t] = acc;
    }
}

// ---------------------------------------------------------------------------
// Kernel 1: MFMA scores + fused local-softmax partial summary (flash-style).
// RT=128: wave tile 64x128 (acc 32xf32x4, all NAMED), so B-operand staging
// and ds_read cost per output row drop ~40% vs RT=64, and Wt L2 re-reads
// halve (1024 blocks). LDS 55 KB -> 2 blocks/CU.
// ---------------------------------------------------------------------------
__global__ __launch_bounds__(256, 2) void scores_kernel(
    const float* __restrict__ ctx, const unsigned short* __restrict__ Wt,
    const float* __restrict__ qh, const float* __restrict__ w2,
    const float* __restrict__ b2, const int* __restrict__ mask,
    float* __restrict__ scores, float* __restrict__ mstat,
    float* __restrict__ lstat, float* __restrict__ part) {
    __shared__ unsigned char lds_a[RT * 144];     // 18432 B
    __shared__ unsigned char lds_b[ATTD_ * 144];  // 36864 B
    const int t = threadIdx.x;
    const int b = blockIdx.y;
    const int ch = blockIdx.x;
    const int s0 = ch * RT;
    const int tx = t & 63;  // lane
    const int w = t >> 6;   // wave
    const int wm = w & 1;   // M half: rows wm*64..+64
    const int wn = w >> 1;  // N half: cols wn*128..+128
    const int frow = tx & 15;
    const int fq = tx >> 4;  // 0..3

    f32x4 cA0, cA1, cA2, cA3, cA4, cA5, cA6, cA7;
    f32x4 cB0, cB1, cB2, cB3, cB4, cB5, cB6, cB7;
    f32x4 cC0, cC1, cC2, cC3, cC4, cC5, cC6, cC7;
    f32x4 cD0, cD1, cD2, cD3, cD4, cD5, cD6, cD7;
    cA0 = cA1 = cA2 = cA3 = cA4 = cA5 = cA6 = cA7 = (f32x4)0.f;
    cB0 = cB1 = cB2 = cB3 = cB4 = cB5 = cB6 = cB7 = (f32x4)0.f;
    cC0 = cC1 = cC2 = cC3 = cC4 = cC5 = cC6 = cC7 = (f32x4)0.f;
    cD0 = cD1 = cD2 = cD3 = cD4 = cD5 = cD6 = cD7 = (f32x4)0.f;

    const float* ctxb = ctx + ((size_t)b * S_ + s0) * CTXD_;
    const int arow = t >> 1;  // staging row 0..127
    const int akq = t & 1;    // 32-float half of the 64-k chunk
    const int bn = t;         // B staging row 0..255

    const unsigned char* aBase = lds_a + (wm * 64 + frow) * 144 + fq * 16;
    const unsigned char* bBase = lds_b + (wn * 128 + frow) * 144 + fq * 16;

    // prefetch chunk 0: A = 32 floats (8 float4), B = 64 bf16 (8 uint4)
    const float* sA = ctxb + (size_t)arow * CTXD_ + akq * 32;
    float4 fa0 = ((const float4*)sA)[0];
    float4 fa1 = ((const float4*)sA)[1];
    float4 fa2 = ((const float4*)sA)[2];
    float4 fa3 = ((const float4*)sA)[3];
    float4 fa4 = ((const float4*)sA)[4];
    float4 fa5 = ((const float4*)sA)[5];
    float4 fa6 = ((const float4*)sA)[6];
    float4 fa7 = ((const float4*)sA)[7];
    const uint4* sB = (const uint4*)(Wt + (size_t)bn * CTXD_);
    uint4 pb0 = sB[0], pb1 = sB[1], pb2 = sB[2], pb3 = sB[3];
    uint4 pb4 = sB[4], pb5 = sB[5], pb6 = sB[6], pb7 = sB[7];

#define MM1(ni, ks)                                                          \
    {                                                                        \
        bf16x8 bf = *(const bf16x8*)(bBase + (ni) * (16 * 144) + (ks) * 64); \
        cA##ni = __builtin_amdgcn_mfma_f32_16x16x32_bf16(a0, bf, cA##ni, 0, 0, 0); \
        cB##ni = __builtin_amdgcn_mfma_f32_16x16x32_bf16(a1, bf, cB##ni, 0, 0, 0); \
        cC##ni = __builtin_amdgcn_mfma_f32_16x16x32_bf16(a2, bf, cC##ni, 0, 0, 0); \
        cD##ni = __builtin_amdgcn_mfma_f32_16x16x32_bf16(a3, bf, cD##ni, 0, 0, 0); \
    }
#define MMK(ks)                                                              \
    {                                                                        \
        bf16x8 a0 = *(const bf16x8*)(aBase + (ks) * 64);                     \
        bf16x8 a1 = *(const bf16x8*)(aBase + 16 * 144 + (ks) * 64);          \
        bf16x8 a2 = *(const bf16x8*)(aBase + 32 * 144 + (ks) * 64);         \
        bf16x8 a3 = *(const bf16x8*)(aBase + 48 * 144 + (ks) * 64);         \
        MM1(0, ks) MM1(1, ks) MM1(2, ks) MM1(3, ks)                          \
        MM1(4, ks) MM1(5, ks) MM1(6, ks) MM1(7, ks)                          \
    }

    #pragma unroll 1
    for (int k0 = 0; k0 < CTXD_; k0 += KT) {
        __syncthreads();  // prior frag reads done; also drains prefetch vmcnt
        {
            uint4 p;
            p.x = pk2(fa0.x, fa0.y); p.y = pk2(fa0.z, fa0.w);
            p.z = pk2(fa1.x, fa1.y); p.w = pk2(fa1.z, fa1.w);
            *(uint4*)(lds_a + arow * 144 + akq * 64) = p;
            p.x = pk2(fa2.x, fa2.y); p.y = pk2(fa2.z, fa2.w);
            p.z = pk2(fa3.x, fa3.y); p.w = pk2(fa3.z, fa3.w);
            *(uint4*)(lds_a + arow * 144 + akq * 64 + 16) = p;
            p.x = pk2(fa4.x, fa4.y); p.y = pk2(fa4.z, fa4.w);
            p.z = pk2(fa5.x, fa5.y); p.w = pk2(fa5.z, fa5.w);
            *(uint4*)(lds_a + arow * 144 + akq * 64 + 32) = p;
            p.x = pk2(fa6.x, fa6.y); p.y = pk2(fa6.z, fa6.w);
            p.z = pk2(fa7.x, fa7.y); p.w = pk2(fa7.z, fa7.w);
            *(uint4*)(lds_a + arow * 144 + akq * 64 + 48) = p;
            uint4* bw = (uint4*)(lds_b + bn * 144);
            bw[0] = pb0; bw[1] = pb1; bw[2] = pb2; bw[3] = pb3;
            bw[4] = pb4; bw[5] = pb5; bw[6] = pb6; bw[7] = pb7;
        }
        __syncthreads();
        // issue next chunk's global loads NOW — overlap with MFMA below
        if (k0 + KT < CTXD_) {
            const float* sA2 = ctxb + (size_t)arow * CTXD_ + (k0 + KT) + akq * 32;
            fa0 = ((const float4*)sA2)[0];
            fa1 = ((const float4*)sA2)[1];
            fa2 = ((const float4*)sA2)[2];
            fa3 = ((const float4*)sA2)[3];
            fa4 = ((const float4*)sA2)[4];
            fa5 = ((const float4*)sA2)[5];
            fa6 = ((const float4*)sA2)[6];
            fa7 = ((const float4*)sA2)[7];
            const uint4* sB2 = (const uint4*)(Wt + (size_t)bn * CTXD_ + (k0 + KT));
            pb0 = sB2[0]; pb1 = sB2[1]; pb2 = sB2[2]; pb3 = sB2[3];
            pb4 = sB2[4]; pb5 = sB2[5]; pb6 = sB2[6]; pb7 = sB2[7];
        }
        MMK(0)
        MMK(1)
    }
#undef MMK
#undef MM1

    // Epilogue: lane holds D[row = wm*64 + mi*16 + fq*4 + r][col = wn*128 + ni*16 + frow]
    const float* qhb = qh + b * ATTD_ + wn * 128;
    const float* w2b = w2 + wn * 128;
    float p00 = 0.f, p01 = 0.f, p02 = 0.f, p03 = 0.f;
    float p10 = 0.f, p11 = 0.f, p12 = 0.f, p13 = 0.f;
    float p20 = 0.f, p21 = 0.f, p22 = 0.f, p23 = 0.f;
    float p30 = 0.f, p31 = 0.f, p32 = 0.f, p33 = 0.f;
#define EPI(ni)                                                              \
    {                                                                        \
        float qv = qhb[(ni) * 16 + frow];                                    \
        float wv = w2b[(ni) * 16 + frow];                                    \
        p00 += fast_tanh(cA##ni[0] + qv) * wv;                               \
        p01 += fast_tanh(cA##ni[1] + qv) * wv;                               \
        p02 += fast_tanh(cA##ni[2] + qv) * wv;                               \
        p03 += fast_tanh(cA##ni[3] + qv) * wv;                               \
        p10 += fast_tanh(cB##ni[0] + qv) * wv;                               \
        p11 += fast_tanh(cB##ni[1] + qv) * wv;                               \
        p12 += fast_tanh(cB##ni[2] + qv) * wv;                               \
        p13 += fast_tanh(cB##ni[3] + qv) * wv;                               \
        p20 += fast_tanh(cC##ni[0] + qv) * wv;                               \
        p21 += fast_tanh(cC##ni[1] + qv) * wv;                               \
        p22 += fast_tanh(cC##ni[2] + qv) * wv;                               \
        p23 += fast_tanh(cC##ni[3] + qv) * wv;                               \
        p30 += fast_tanh(cD##ni[0] + qv) * wv;                               \
        p31 += fast_tanh(cD##ni[1] + qv) * wv;                               \
        p32 += fast_tanh(cD##ni[2] + qv) * wv;                               \
        p33 += fast_tanh(cD##ni[3] + qv) * wv;                               \
    }
    EPI(0) EPI(1) EPI(2) EPI(3) EPI(4) EPI(5) EPI(6) EPI(7)
#undef EPI
    // reduce across the 16 frow lanes
#define RED(P) P += __shfl_xor(P, off, 64);
    #pragma unroll
    for (int off = 1; off <= 8; off <<= 1) {
        RED(p00) RED(p01) RED(p02) RED(p03)
        RED(p10) RED(p11) RED(p12) RED(p13)
        RED(p20) RED(p21) RED(p22) RED(p23)
        RED(p30) RED(p31) RED(p32) RED(p33)
    }
#undef RED
    // combine the two N-half waves via LDS (reuse lds_a): sred[wn*128 + row]
    float* sred = (float*)lds_a;  // 256 floats
    __syncthreads();              // all MFMA-phase LDS reads done
    if (frow == 0) {
        const int base = wn * 128 + wm * 64 + fq * 4;
        sred[base + 0] = p00;  sred[base + 1] = p01;
        sred[base + 2] = p02;  sred[base + 3] = p03;
        sred[base + 16 + 0] = p10; sred[base + 16 + 1] = p11;
        sred[base + 16 + 2] = p12; sred[base + 16 + 3] = p13;
        sred[base + 32 + 0] = p20; sred[base + 32 + 1] = p21;
        sred[base + 32 + 2] = p22; sred[base + 32 + 3] = p23;
        sred[base + 48 + 0] = p30; sred[base + 48 + 1] = p31;
        sred[base + 48 + 2] = p32; sred[base + 48 + 3] = p33;
    }
    __syncthreads();
    // --- local softmax over this block's 128 rows (threads 0..127) ---
    float* wl = (float*)lds_b;             // 128 weights
    float* red2 = (float*)(lds_b + 512);   // 4 slots
    float sc = 0.f;
    bool msk = false;
    if (t < 128) {
        const int s = s0 + t;
        sc = sred[t] + sred[128 + t] + b2[0];
        msk = (mask[b * S_ + s] == 0);
        if (msk) sc = MASKED_SCORE;
        scores[b * S_ + s] = sc;
        float mloc = sc;
        #pragma unroll
        for (int off = 1; off <= 32; off <<= 1)
            mloc = fmaxf(mloc, __shfl_xor(mloc, off, 64));
        if ((t & 63) == 0) red2[t >> 6] = mloc;
    }
    __syncthreads();
    if (t < 128) {
        const float mg = fmaxf(red2[0], red2[1]);
        const float ws = msk ? 0.f : __expf(sc - mg);
        float lloc = ws;
        #pragma unroll
        for (int off = 1; off <= 32; off <<= 1)
            lloc += __shfl_xor(lloc, off, 64);
        if ((t & 63) == 0) red2[2 + (t >> 6)] = lloc;
        wl[t] = ws;
        if (t == 0) mstat[b * NCH + ch] = mg;
    }
    __syncthreads();
    if (t == 0) lstat[b * NCH + ch] = red2[2] + red2[3];
    // --- partial summary: Σ_s w_s · ctx[s,:]  (ctx rows are L2-hot) ---
    const int col = t & 63;  // float4 col idx (cols col and col+64)
    const int q = t >> 6;    // s ≡ q (mod 4)
    float4 alo = make_float4(0.f, 0.f, 0.f, 0.f);
    float4 ahi = make_float4(0.f, 0.f, 0.f, 0.f);
    #pragma unroll 4
    for (int s = q; s < RT; s += 4) {
        const float al = wl[s];
        const float4* row = (const float4*)(ctxb + (size_t)s * CTXD_);
        float4 v0 = row[col];
        float4 v1 = row[col + 64];
        alo.x += v0.x * al; alo.y += v0.y * al;
        alo.z += v0.z * al; alo.w += v0.w * al;
        ahi.x += v1.x * al; ahi.y += v1.y * al;
        ahi.z += v1.z * al; ahi.w += v1.w * al;
    }
    float4* buf = (float4*)(lds_b + 1024);  // disjoint from wl/red2
    buf[q * 128 + col] = alo;
    buf[q * 128 + col + 64] = ahi;
    __syncthreads();
    if (t < 128) {
        float4 a0 = buf[t], a1 = buf[128 + t], a2 = buf[256 + t], a3 = buf[384 + t];
        float4 r;
        r.x = a0.x + a1.x + a2.x + a3.x;
        r.y = a0.y + a1.y + a2.y + a3.y;
        r.z = a0.z + a1.z + a2.z + a3.z;
        r.w = a0.w + a1.w + a2.w + a3.w;
        ((float4*)(part + ((size_t)(b * NCH + ch)) * CTXD_))[t] = r;
    }
}

// ---------------------------------------------------------------------------
// Kernel 2: combine — grid (4, B). Each block redoes the cheap per-chunk
// stats reduce (NCH=32), then handles a 128-col slice of summary and a
// 1024-row slice of alphas.
// ---------------------------------------------------------------------------
__global__ __launch_bounds__(256) void combine_kernel(
    const float* __restrict__ mstat, const float* __restrict__ lstat,
    const float* __restrict__ part, const float* __restrict__ scores,
    float* __restrict__ alphas, float* __restrict__ summary) {
    const int b = blockIdx.y, seg = blockIdx.x, t = threadIdx.x;
    __shared__ float e[NCH];
    __shared__ float gstat[2];  // m, invl
    if (t < NCH) {
        const float mi = mstat[b * NCH + t];
        const float li = lstat[b * NCH + t];
        float m = mi;
        #pragma unroll
        for (int off = 1; off <= 16; off <<= 1)
            m = fmaxf(m, __shfl_xor(m, off, 64));
        const float ei = __expf(mi - m);  // all-masked chunk: underflows to 0
        float l = ei * li;
        #pragma unroll
        for (int off = 1; off <= 16; off <<= 1)
            l += __shfl_xor(l, off, 64);
        e[t] = ei;
        if (t == 0) { gstat[0] = m; gstat[1] = 1.0f / l; }
    }
    __syncthreads();
    const float m = gstat[0], il = gstat[1];
    // summary slice: cols [seg*128, seg*128+128) = 32 float4
    const int c4 = t & 31;   // float4 within slice
    const int grp = t >> 5;  // 0..7: chunk phase
    float4 acc = make_float4(0.f, 0.f, 0.f, 0.f);
    for (int chv = grp; chv < NCH; chv += 8) {
        const float ei = e[chv];
        float4 v =
            ((const float4*)(part + ((size_t)(b * NCH + chv)) * CTXD_ + seg * 128))[c4];
        acc.x += ei * v.x; acc.y += ei * v.y;
        acc.z += ei * v.z; acc.w += ei * v.w;
    }
    __shared__ float4 buf[8][32];
    buf[grp][c4] = acc;
    __syncthreads();
    if (t < 32) {
        float4 r = make_float4(0.f, 0.f, 0.f, 0.f);
        #pragma unroll
        for (int g = 0; g < 8; ++g) {
            float4 v = buf[g][t];
            r.x += v.x; r.y += v.y; r.z += v.z; r.w += v.w;
        }
        r.x *= il; r.y *= il; r.z *= il; r.w *= il;
        ((float4*)(summary + (size_t)b * CTXD_ + seg * 128))[t] = r;
    }
    // alphas slice: s in [seg*1024, +1024)
    const int sbase = seg * 1024;
    #pragma unroll
    for (int i = 0; i < 4; ++i) {
        const int s = sbase + i * 256 + t;
        alphas[b * S_ + s] = __expf(scores[b * S_ + s] - m) * il;
    }
}

extern "C" void kernel_launch(void* const* d_in, const int* in_sizes, int n_in,
                              void* d_out, int out_size, void* d_ws,
                              size_t ws_size, hipStream_t stream) {
    const float* qry = (const float*)d_in[0];
    const float* ctx = (const float*)d_in[1];
    const int* mask = (const int*)d_in[2];
    const float* W = (const float*)d_in[3];
    const float* bias = (const float*)d_in[4];
    const float* w2 = (const float*)d_in[5];
    const float* b2 = (const float*)d_in[6];

    float* out = (float*)d_out;
    float* alphas = out;                         // B*S
    float* summary = out + B_ * S_;              // B*CTXD
    float* scores = out + B_ * S_ + B_ * CTXD_;  // B*S

    // ws layout: [Wt bf16 256KB][qh 32KB][mstat 4KB][lstat 4KB][part 2MB]
    unsigned short* Wt = (unsigned short*)d_ws;
    float* qh = (float*)((char*)d_ws + (size_t)ATTD_ * CTXD_ * 2);
    float* mstat = qh + B_ * ATTD_;
    float* lstat = mstat + B_ * NCH;
    float* part = lstat + B_ * NCH;

    prep_kernel<<<64, 256, 0, stream>>>(W, qry, bias, Wt, qh);
    scores_kernel<<<dim3(NCH, B_), 256, 0, stream>>>(ctx, Wt, qh, w2, b2, mask,
                                                     scores, mstat, lstat, part);
    combine_kernel<<<dim3(4, B_), 256, 0, stream>>>(mstat, lstat, part, scores,
                                                    alphas, summary);
}